// Round 2
// baseline (326.241 us; speedup 1.0000x reference)
//
#include <hip/hip_runtime.h>
#include <math.h>

#define NN 100000
#define NP 100032   // 64 * 1563 (padded node count)
#define NE 2000000
#define FIN 32
#define H 32
#define NC 40

#define NBK 196      // coarse buckets: dst>>9 (512 nodes each)
#define BSH 9
#define CAP 10880    // per-bucket capacity: mean 10240 + ~6.3 sigma (trimmed from 11264 to fund ofs2)
#define NSL 4        // src slices (src>>15): ~2.1 MB dense table slice per phase < 4 MiB XCD L2
#define EPT 16
#define EPB (256 * EPT)  // 4096 edges per block

typedef _Float16 half_t;
typedef __attribute__((ext_vector_type(8))) _Float16 half8;
typedef __attribute__((ext_vector_type(4))) _Float16 half4;
typedef __attribute__((ext_vector_type(4))) float f32x4;

__device__ __forceinline__ float sigm_(float x) {
    return 1.0f / (1.0f + __expf(-x));
}
__device__ __forceinline__ float tanh_(float x) {
    x = fminf(fmaxf(x, -20.0f), 20.0f);
    float e = __expf(2.0f * x);
    return (e - 1.0f) / (e + 1.0f);
}

// ---------- phase A: coarse-bucket scatter with LDS staging ----------
__global__ __launch_bounds__(256) void kA_bucket(const int* __restrict__ ei,
                                                 const float* __restrict__ ew,
                                                 int* __restrict__ gcur,
                                                 long long* __restrict__ rec) {
    __shared__ long long recs[EPB];   // 32 KB bucket-sorted records
    __shared__ int gdst[EPB];         // 16 KB absolute global slot per record
    __shared__ int cnt[NBK], base[NBK], sofs[NBK];
    __shared__ int ssc[256];
    int tid = threadIdx.x;
    for (int i = tid; i < NBK; i += 256) cnt[i] = 0;
    __syncthreads();
    int e0 = blockIdx.x * EPB;
    int dcache[EPT];
#pragma unroll
    for (int i = 0; i < EPT; ++i) {
        int e = e0 + i * 256 + tid;
        dcache[i] = (e < NE) ? ei[NE + e] : -1;
        if (e < NE) atomicAdd(&cnt[dcache[i] >> BSH], 1);
    }
    __syncthreads();
    int cv = (tid < NBK) ? cnt[tid] : 0;
    ssc[tid] = cv;
    __syncthreads();
    for (int off = 1; off < 256; off <<= 1) {
        int v = (tid >= off) ? ssc[tid - off] : 0;
        __syncthreads();
        ssc[tid] += v;
        __syncthreads();
    }
    if (tid < NBK) {
        sofs[tid] = ssc[tid] - cv;
        base[tid] = atomicAdd(&gcur[tid], cv);  // one global atomic per (block,bucket)
        cnt[tid] = 0;                           // reuse as rank cursor
    }
    __syncthreads();
#pragma unroll
    for (int i = 0; i < EPT; ++i) {
        int e = e0 + i * 256 + tid;
        if (e < NE) {
            int d = dcache[i], s = ei[e];
            int b = d >> BSH;
            int r = atomicAdd(&cnt[b], 1);
            int slot = sofs[b] + r;
            int pos = base[b] + r;
            int lo = s | ((d & 511) << 17);
            recs[slot] = (long long)(unsigned)lo |
                         ((long long)__float_as_int(ew[e]) << 32);
            gdst[slot] = (pos < CAP) ? (b * CAP + pos) : -1;  // overflow guard
        }
    }
    __syncthreads();
    int nrec = min(EPB, NE - e0);
    for (int i = tid; i < nrec; i += 256) {
        int gd = gdst[i];
        if (gd >= 0) rec[gd] = recs[i];
    }
}

// ---------- phase B: per-bucket counting sort by (src_slice, dst_local) ----------
// Round-15: 2048 bins = 4 src-slices x 512 dsts, slice-major. Per agg phase s all
// waves gather from a ~2.1 MB dense table slice -> L2-resident (was 18x re-fetch).
__global__ __launch_bounds__(256) void kB_sort(const int* __restrict__ gcur,
                                               const int2* __restrict__ rec,
                                               int2* __restrict__ evs,
                                               int* __restrict__ ofs2,
                                               int* __restrict__ cnt4) {
    __shared__ int hist[2048], lofs[2048], ssc[256];
    int tid = threadIdx.x, b = blockIdx.x;
    int nb0 = b << BSH;
    int nnodes = min(512, NN - nb0);
    int cntb = min(gcur[b], CAP);
    for (int i = tid; i < 2048; i += 256) hist[i] = 0;
    __syncthreads();
    const int2* rb = rec + (size_t)b * CAP;
    for (int i = tid; i < cntb; i += 256) {
        int rx = rb[i].x;
        int bin = (((rx & 0x1FFFF) >> 15) << BSH) | ((rx >> 17) & 511);
        atomicAdd(&hist[bin], 1);
    }
    __syncthreads();
    // scan 2048 bins: 8 contiguous bins/thread, block scan of per-thread sums
    int base = tid * 8, ls = 0, lh[8];
#pragma unroll
    for (int j = 0; j < 8; ++j) {
        lh[j] = hist[base + j];
        ls += lh[j];
    }
    ssc[tid] = ls;
    __syncthreads();
    for (int off = 1; off < 256; off <<= 1) {
        int v = (tid >= off) ? ssc[tid - off] : 0;
        __syncthreads();
        ssc[tid] += v;
        __syncthreads();
    }
    int ex = ssc[tid] - ls;
#pragma unroll
    for (int j = 0; j < 8; ++j) {
        lofs[base + j] = ex;
        ex += lh[j];
    }
    __syncthreads();
    // per-node CSR meta: 4 slice starts + packed u8x4 counts
    // (per-(node,slice) degree ~ Poisson(5); max for this input ~25 << 255)
    for (int l = tid; l < nnodes; l += 256) {
        int c0 = hist[l], c1 = hist[512 + l], c2 = hist[1024 + l], c3 = hist[1536 + l];
        cnt4[nb0 + l] = c0 | (c1 << 8) | (c2 << 16) | (c3 << 24);
        ofs2[0 * NN + nb0 + l] = b * CAP + lofs[l];
        ofs2[1 * NN + nb0 + l] = b * CAP + lofs[512 + l];
        ofs2[2 * NN + nb0 + l] = b * CAP + lofs[1024 + l];
        ofs2[3 * NN + nb0 + l] = b * CAP + lofs[1536 + l];
    }
    __syncthreads();
    for (int i = tid; i < 2048; i += 256) hist[i] = 0;
    __syncthreads();
    int2* eb = evs + (size_t)b * CAP;
    for (int i = tid; i < cntb; i += 256) {
        int2 r = rb[i];
        int bin = (((r.x & 0x1FFFF) >> 15) << BSH) | ((r.x >> 17) & 511);
        int rk = atomicAdd(&hist[bin], 1);
        eb[lofs[bin] + rk] = make_int2(r.x & 0x1FFFF, r.y);
    }
}

// ---------- stage 1 of layer-2 weight fold (also zeroes gcur, replaces memset) ----------
__global__ __launch_bounds__(256) void k_wpre(const float* __restrict__ W2m,
                                              const float* __restrict__ wih2,
                                              float* __restrict__ M2,
                                              int* __restrict__ gcur) {
    int i = blockIdx.x * 256 + threadIdx.x;
    if (i < NBK) gcur[i] = 0;
    if (i >= NC * 3 * NC) return;
    int u = i / (3 * NC), col = i % (3 * NC);
    float acc = 0.f;
#pragma unroll
    for (int t = 0; t < NC; ++t) acc += W2m[u * NC + t] * wih2[col * NC + t];
    M2[i] = acc;
}

// ---------- build MFMA B-fragment-linear fp16 weight tables ----------
__global__ __launch_bounds__(256) void k_wc(const float* __restrict__ W1m,
                                            const float* __restrict__ wih1,
                                            const float* __restrict__ W2p,
                                            const float* __restrict__ M2,
                                            const float* __restrict__ whh1,
                                            const float* __restrict__ whh2,
                                            half_t* __restrict__ W1sw,
                                            half_t* __restrict__ W2sw) {
    int i = blockIdx.x * 256 + threadIdx.x;
    if (i < 8192) {
        int j = i & 7, lane = (i >> 3) & 63, ct = (i >> 9) & 7, s = i >> 12;
        int k = s * 32 + (lane >> 4) * 8 + j;
        int col = ct * 16 + (lane & 15);
        int g = col >> 5, jj = col & 31;
        float v = 0.f;
        if (g <= 2) {
            if (k < 32) {  // input side (agg): fold W1m @ wih1^T
                float acc = 0.f;
#pragma unroll
                for (int t = 0; t < H; ++t) acc += W1m[k * H + t] * wih1[(g * H + jj) * H + t];
                v = acc;
            } else if (g < 2) {  // r,z hidden side
                v = whh1[(g * H + jj) * H + (k - 32)];
            }                     // g==2 (i_n), k>=32 -> 0
        } else {                  // g==3 (h_n): hidden side only
            if (k >= 32) v = whh1[(2 * H + jj) * H + (k - 32)];
        }
        W1sw[i] = (half_t)v;
    } else if (i < 8192 + 18432) {
        int i2 = i - 8192;
        int j = i2 & 7, lane = (i2 >> 3) & 63;
        int tt = i2 >> 9;  // 0..35
        int ct = tt % 12, s = tt / 12;
        int k = s * 32 + (lane >> 4) * 8 + j;  // 0..95
        int col = ct * 16 + (lane & 15);       // 0..191
        int g = col / 48, jj = col % 48;
        float v = 0.f;
        if (jj < NC) {
            if (g <= 2) {
                if (k < 32) {  // input side (aggX): W2p @ M2 (stage-1 precomputed)
                    float acc = 0.f;
#pragma unroll
                    for (int u = 0; u < NC; ++u)
                        acc += W2p[k * NC + u] * M2[u * 3 * NC + g * NC + jj];
                    v = acc;
                } else if (k < 72 && g < 2) {  // r,z hidden side
                    v = whh2[(g * NC + jj) * NC + (k - 32)];
                }
            } else {  // g==3 (h_n)
                if (k >= 32 && k < 72) v = whh2[(2 * NC + jj) * NC + (k - 32)];
            }
        }
        W2sw[i2] = (half_t)v;
    }
}

// ---------- K1: h1 = x @ W1p -> fp16 into Xc1 cols 32..63 AND dense Hd [NN][32] ----------
// Hd halves the gather cache footprint vs the 128B-stride Xc rows (dense 64 B lines).
__global__ __launch_bounds__(256) void k1_proj(const float* __restrict__ x,
                                               const float* __restrict__ Wp,
                                               half_t* __restrict__ Xc1,
                                               half_t* __restrict__ Hd) {
    __shared__ float sWp[FIN * H];
    __shared__ float sx[8][FIN];
    int tid = threadIdx.x;
    for (int i = tid; i < FIN * H; i += 256) sWp[i] = Wp[i];
    int nb = blockIdx.x * 8;
    int nl = tid >> 5, j = tid & 31;
    int n = nb + nl;
    if (n < NN) sx[nl][j] = x[(size_t)n * FIN + j];
    __syncthreads();
    float acc = 0.f;
#pragma unroll
    for (int k = 0; k < FIN; ++k) acc += sx[nl][k] * sWp[k * H + j];
    if (n < NN) {
        half_t hv = (half_t)acc;
        Xc1[(size_t)n * 64 + 32 + j] = hv;
        Hd[(size_t)n * 32 + j] = hv;
    }
}

// ---------- K4: h2 = hrelu @ W2p -> fp16 into Xc2 cols 32..71 (stride 96); zero pad 72..95 ----------
__global__ __launch_bounds__(320) void k4_proj2(const half_t* __restrict__ Hh,
                                                const float* __restrict__ Wp,
                                                half_t* __restrict__ Xc2) {
    __shared__ float sWp[FIN * NC];
    __shared__ float shn[8][FIN];
    int tid = threadIdx.x;
    for (int i = tid; i < FIN * NC; i += 320) sWp[i] = Wp[i];
    int nb = blockIdx.x * 8;
    if (tid < 256) {
        int r = tid >> 5, c = tid & 31;
        shn[r][c] = (float)Hh[(size_t)(nb + r) * 32 + c];
    }
    // zero K-pad cols 72..95 (stale scratch can be fp16-NaN; MFMA 0*NaN = NaN)
    if (tid < 192) {
        int r = tid / 24, c = tid % 24;
        Xc2[(size_t)(nb + r) * 96 + 72 + c] = (half_t)0.f;
    }
    __syncthreads();
    int nl = tid / NC, j = tid % NC;
    int n = nb + nl;
    float acc = 0.f;
#pragma unroll
    for (int k = 0; k < FIN; ++k) acc += shn[nl][k] * sWp[k * NC + j];
    if (n < NN) Xc2[(size_t)n * 96 + 32 + j] = (half_t)acc;
}

// ---------- aggregation: src-slice-phased fp16 gather, fp32 accum ----------
// Per slice phase, the whole grid's gathers hit one ~2.1 MB dense table slice
// (L2-resident). Block barrier between phases keeps resident waves in phase.
// evs stream loads are nontemporal so they don't evict the slice.
// Grid is exactly NN*8/256 blocks -> no inactive threads (barrier-safe).
template <int DSTR>
__global__ __launch_bounds__(256) void k_aggh(const int* __restrict__ ofs2,
                                              const int* __restrict__ cnt4,
                                              const int2* __restrict__ evs,
                                              const half_t* __restrict__ src,
                                              half_t* __restrict__ dst) {
    int idx = blockIdx.x * 256 + threadIdx.x;
    int n = idx >> 3, q = idx & 7;
    const half4* s4 = (const half4*)src + q;       // lane's 8B column slice (rows = 8 half4)
    const long long* ev8 = (const long long*)evs;  // packed (src, w)
    int cw = cnt4[n];
    float acc[4] = {0.f, 0.f, 0.f, 0.f};
    for (int s = 0; s < NSL; ++s) {
        int s0 = ofs2[s * NN + n];
        int e1 = s0 + ((cw >> (8 * s)) & 255);
        int e = s0;
        for (; e + 4 <= e1; e += 4) {
            long long r0 = __builtin_nontemporal_load(ev8 + e);
            long long r1 = __builtin_nontemporal_load(ev8 + e + 1);
            long long r2 = __builtin_nontemporal_load(ev8 + e + 2);
            long long r3 = __builtin_nontemporal_load(ev8 + e + 3);
            half4 h0 = s4[(size_t)(r0 & 0x1FFFF) * 8];
            half4 h1 = s4[(size_t)(r1 & 0x1FFFF) * 8];
            half4 h2 = s4[(size_t)(r2 & 0x1FFFF) * 8];
            half4 h3 = s4[(size_t)(r3 & 0x1FFFF) * 8];
            float w0 = __int_as_float((int)(r0 >> 32));
            float w1 = __int_as_float((int)(r1 >> 32));
            float w2 = __int_as_float((int)(r2 >> 32));
            float w3 = __int_as_float((int)(r3 >> 32));
#pragma unroll
            for (int t = 0; t < 4; ++t) {
                acc[t] += w0 * (float)h0[t];
                acc[t] += w1 * (float)h1[t];
                acc[t] += w2 * (float)h2[t];
                acc[t] += w3 * (float)h3[t];
            }
        }
        for (; e < e1; ++e) {
            long long r = __builtin_nontemporal_load(ev8 + e);
            float w = __int_as_float((int)(r >> 32));
            half4 hv = s4[(size_t)(r & 0x1FFFF) * 8];
#pragma unroll
            for (int t = 0; t < 4; ++t) acc[t] += w * (float)hv[t];
        }
        __syncthreads();  // phase boundary: keep block's gathers within one slice
    }
    half4 o;
#pragma unroll
    for (int t = 0; t < 4; ++t) o[t] = (half_t)acc[t];
    *(half4*)(dst + (size_t)n * DSTR + q * 4) = o;
}

// ---------- K3: GRU layer1 + relu via MFMA. 4 waves x 16 nodes, no LDS ----------
__global__ __launch_bounds__(256) void k3m(const half_t* __restrict__ Xc1,
                                           const half8* __restrict__ W1sw,
                                           const float* __restrict__ bih,
                                           const float* __restrict__ bhh,
                                           half_t* __restrict__ Hh) {
    int tid = threadIdx.x;
    int wave = tid >> 6, lane = tid & 63;
    int m16 = lane & 15, q = lane >> 4;
    int nb = blockIdx.x * 64 + wave * 16;
    const half8* xr = (const half8*)(Xc1 + (size_t)(nb + m16) * 64);
    half8 a0 = xr[q];      // k = q*8..q*8+7
    half8 a1 = xr[4 + q];  // k = 32+q*8..
    f32x4 acc[8];
#pragma unroll
    for (int ct = 0; ct < 8; ++ct) acc[ct] = (f32x4){0.f, 0.f, 0.f, 0.f};
#pragma unroll
    for (int ct = 0; ct < 8; ++ct) {
        acc[ct] = __builtin_amdgcn_mfma_f32_16x16x32_f16(a0, W1sw[ct * 64 + lane], acc[ct], 0, 0, 0);
        acc[ct] = __builtin_amdgcn_mfma_f32_16x16x32_f16(a1, W1sw[(8 + ct) * 64 + lane], acc[ct], 0, 0, 0);
    }
#pragma unroll
    for (int ct = 0; ct < 2; ++ct) {
        int j = ct * 16 + m16;
        float br = bih[j] + bhh[j];
        float bz = bih[H + j] + bhh[H + j];
        float bi = bih[2 * H + j], bh = bhh[2 * H + j];
#pragma unroll
        for (int m = 0; m < 4; ++m) {
            int node = nb + q * 4 + m;  // C/D: row = quad*4 + reg, col = lane&15
            float r = sigm_(acc[ct][m] + br);
            float z = sigm_(acc[2 + ct][m] + bz);
            float ng = tanh_(acc[4 + ct][m] + bi + r * (acc[6 + ct][m] + bh));
            float hj = (float)Xc1[(size_t)node * 64 + 32 + j];
            float o = fmaxf((1.f - z) * ng + z * hj, 0.f);
            if (node < NN) Hh[(size_t)node * 32 + j] = (half_t)o;
        }
    }
}

// ---------- K6: GRU layer2 + log_softmax via MFMA + shfl reduce, no LDS ----------
__global__ __launch_bounds__(256) void k6m(const half_t* __restrict__ Xc2,
                                           const half8* __restrict__ W2sw,
                                           const float* __restrict__ bih,
                                           const float* __restrict__ bhh,
                                           float* __restrict__ out) {
    int tid = threadIdx.x;
    int wave = tid >> 6, lane = tid & 63;
    int m16 = lane & 15, q = lane >> 4;
    int nb = blockIdx.x * 64 + wave * 16;
    const half8* xr = (const half8*)(Xc2 + (size_t)(nb + m16) * 96);
    half8 a0 = xr[q], a1 = xr[4 + q], a2 = xr[8 + q];
    f32x4 acc[12];
#pragma unroll
    for (int ct = 0; ct < 12; ++ct) acc[ct] = (f32x4){0.f, 0.f, 0.f, 0.f};
#pragma unroll
    for (int ct = 0; ct < 12; ++ct) {
        acc[ct] = __builtin_amdgcn_mfma_f32_16x16x32_f16(a0, W2sw[ct * 64 + lane], acc[ct], 0, 0, 0);
        acc[ct] = __builtin_amdgcn_mfma_f32_16x16x32_f16(a1, W2sw[(12 + ct) * 64 + lane], acc[ct], 0, 0, 0);
        acc[ct] = __builtin_amdgcn_mfma_f32_16x16x32_f16(a2, W2sw[(24 + ct) * 64 + lane], acc[ct], 0, 0, 0);
    }
    float v[3][4];
#pragma unroll
    for (int ct = 0; ct < 3; ++ct) {
        int j = ct * 16 + m16;
        int jc = (j < NC) ? j : (NC - 1);  // clamp (lanes with j>=40 produce unused values)
        float br = bih[jc] + bhh[jc];
        float bz = bih[NC + jc] + bhh[NC + jc];
        float bi = bih[2 * NC + jc], bh = bhh[2 * NC + jc];
#pragma unroll
        for (int m = 0; m < 4; ++m) {
            int node = nb + q * 4 + m;
            float r = sigm_(acc[ct][m] + br);
            float z = sigm_(acc[3 + ct][m] + bz);
            float ng = tanh_(acc[6 + ct][m] + bi + r * (acc[9 + ct][m] + bh));
            float hj = (float)Xc2[(size_t)node * 96 + 32 + jc];
            v[ct][m] = (1.f - z) * ng + z * hj;
        }
    }
    bool v2ok = (m16 < 8);  // ct=2 covers j=32..39 only for m16<8
#pragma unroll
    for (int m = 0; m < 4; ++m) {
        float mx = fmaxf(v[0][m], v[1][m]);
        if (v2ok) mx = fmaxf(mx, v[2][m]);
#pragma unroll
        for (int d = 1; d < 16; d <<= 1) mx = fmaxf(mx, __shfl_xor(mx, d));
        float se = __expf(v[0][m] - mx) + __expf(v[1][m] - mx) +
                   (v2ok ? __expf(v[2][m] - mx) : 0.f);
#pragma unroll
        for (int d = 1; d < 16; d <<= 1) se += __shfl_xor(se, d);
        float ls = mx + __logf(se);
        int node = nb + q * 4 + m;
        if (node < NN) {
            out[(size_t)node * NC + m16] = v[0][m] - ls;
            out[(size_t)node * NC + 16 + m16] = v[1][m] - ls;
            if (v2ok) out[(size_t)node * NC + 32 + m16] = v[2][m] - ls;
        }
    }
}

extern "C" void kernel_launch(void* const* d_in, const int* in_sizes, int n_in,
                              void* d_out, int out_size, void* d_ws, size_t ws_size,
                              hipStream_t stream) {
    const float* x = (const float*)d_in[0];
    const int* ei = (const int*)d_in[1];
    const float* ew = (const float*)d_in[2];
    const float* W1p = (const float*)d_in[3];
    const float* W1m = (const float*)d_in[4];
    const float* g1wih = (const float*)d_in[5];
    const float* g1whh = (const float*)d_in[6];
    const float* g1bih = (const float*)d_in[7];
    const float* g1bhh = (const float*)d_in[8];
    const float* W2p = (const float*)d_in[9];
    const float* W2m = (const float*)d_in[10];
    const float* g2wih = (const float*)d_in[11];
    const float* g2whh = (const float*)d_in[12];
    const float* g2bih = (const float*)d_in[13];
    const float* g2bhh = (const float*)d_in[14];
    float* ws = (float*)d_ws;

    // workspace layout (float indices), ~44.7 MB total:
    //  Xc   [0, 4801536)      fp16 activations: [NP][64] L1 / [NP][96] L2
    //  Hd   [3201024,4801536) dense [NN][32] fp16 L1 gather table (slack of Xc's L1 use;
    //                         dead before layer-2 Xc[96] overwrites it)
    //  Hh   [4801536,6402048) dense [NN][32] fp16 hrelu table
    //  rec  [0, 4264960)      CSR-build scratch, overlays Xc (dead before k1)
    //  evs  [6402048,10667008) 196*CAP sorted records
    //  ofs2 [10667008,11067008) int[4][NN] per-slice segment starts
    //  cnt4 [11067008,11167008) u8x4 per-(node,slice) counts
    //  gcur [11167008,11167264)
    //  W1sw/W2sw/M2 tail
    half_t* Xc = (half_t*)ws;
    half_t* Hd = (half_t*)(ws + 3201024);
    half_t* Hh = (half_t*)(ws + 4801536);
    int2* rec = (int2*)ws;
    int2* evs = (int2*)(ws + 6402048);
    int* ofs2 = (int*)(ws + 10667008);
    int* cnt4 = (int*)(ws + 11067008);
    int* gcur = (int*)(ws + 11167008);
    half_t* W1sw = (half_t*)(ws + 11167264);
    half_t* W2sw = W1sw + 8192;
    float* M2 = ws + 11180576;
    float* out = (float*)d_out;

    // ---- CSR build (shared by both layers) ----
    k_wpre<<<(NC * 3 * NC + 255) / 256, 256, 0, stream>>>(W2m, g2wih, M2, gcur);
    kA_bucket<<<(NE + EPB - 1) / EPB, 256, 0, stream>>>(ei, ew, gcur, (long long*)rec);
    kB_sort<<<NBK, 256, 0, stream>>>(gcur, rec, evs, ofs2, cnt4);
    k_wc<<<(8192 + 18432 + 255) / 256, 256, 0, stream>>>(
        W1m, g1wih, W2p, M2, g1whh, g2whh, W1sw, W2sw);

    // ---- layer 1 ----
    k1_proj<<<NN / 8, 256, 0, stream>>>(x, W1p, Xc, Hd);
    k_aggh<64><<<NN * 8 / 256, 256, 0, stream>>>(ofs2, cnt4, evs, Hd, Xc);
    k3m<<<NP / 64, 256, 0, stream>>>(Xc, (const half8*)W1sw, g1bih, g1bhh, Hh);

    // ---- layer 2 ----
    k4_proj2<<<NN / 8, 320, 0, stream>>>(Hh, W2p, Xc);
    k_aggh<96><<<NN * 8 / 256, 256, 0, stream>>>(ofs2, cnt4, evs, Hh, Xc);
    k6m<<<NP / 64, 256, 0, stream>>>(Xc, (const half8*)W2sw, g2bih, g2bhh, out);
}

// Round 3
// 298.358 us; speedup vs baseline: 1.0935x; 1.0935x over previous
//
#include <hip/hip_runtime.h>
#include <math.h>

#define NN 100000
#define NP 100032   // 64 * 1563 (padded node count)
#define NE 2000000
#define FIN 32
#define H 32
#define NC 40

#define NBK 196      // coarse buckets: dst>>9 (512 nodes each)
#define BSH 9
#define CAP 10880    // per-bucket capacity: mean 10240 + ~6.3 sigma
#define NSL 4        // src slices (src>>15): ~2.1 MB dense table slice < 4 MiB XCD L2
#define EPT 16
#define EPB (256 * EPT)  // 4096 edges per block

typedef _Float16 half_t;
typedef __attribute__((ext_vector_type(8))) _Float16 half8;
typedef __attribute__((ext_vector_type(4))) _Float16 half4;
typedef __attribute__((ext_vector_type(4))) float f32x4;
typedef long long ll2 __attribute__((ext_vector_type(2)));

__device__ __forceinline__ float sigm_(float x) {
    return 1.0f / (1.0f + __expf(-x));
}
__device__ __forceinline__ float tanh_(float x) {
    x = fminf(fmaxf(x, -20.0f), 20.0f);
    float e = __expf(2.0f * x);
    return (e - 1.0f) / (e + 1.0f);
}

// ---------- phase A: coarse-bucket scatter with LDS staging ----------
__global__ __launch_bounds__(256) void kA_bucket(const int* __restrict__ ei,
                                                 const float* __restrict__ ew,
                                                 int* __restrict__ gcur,
                                                 long long* __restrict__ rec) {
    __shared__ long long recs[EPB];   // 32 KB bucket-sorted records
    __shared__ int gdst[EPB];         // 16 KB absolute global slot per record
    __shared__ int cnt[NBK], base[NBK], sofs[NBK];
    __shared__ int ssc[256];
    int tid = threadIdx.x;
    for (int i = tid; i < NBK; i += 256) cnt[i] = 0;
    __syncthreads();
    int e0 = blockIdx.x * EPB;
    int dcache[EPT];
#pragma unroll
    for (int i = 0; i < EPT; ++i) {
        int e = e0 + i * 256 + tid;
        dcache[i] = (e < NE) ? ei[NE + e] : -1;
        if (e < NE) atomicAdd(&cnt[dcache[i] >> BSH], 1);
    }
    __syncthreads();
    int cv = (tid < NBK) ? cnt[tid] : 0;
    ssc[tid] = cv;
    __syncthreads();
    for (int off = 1; off < 256; off <<= 1) {
        int v = (tid >= off) ? ssc[tid - off] : 0;
        __syncthreads();
        ssc[tid] += v;
        __syncthreads();
    }
    if (tid < NBK) {
        sofs[tid] = ssc[tid] - cv;
        base[tid] = atomicAdd(&gcur[tid], cv);  // one global atomic per (block,bucket)
        cnt[tid] = 0;                           // reuse as rank cursor
    }
    __syncthreads();
#pragma unroll
    for (int i = 0; i < EPT; ++i) {
        int e = e0 + i * 256 + tid;
        if (e < NE) {
            int d = dcache[i], s = ei[e];
            int b = d >> BSH;
            int r = atomicAdd(&cnt[b], 1);
            int slot = sofs[b] + r;
            int pos = base[b] + r;
            int lo = s | ((d & 511) << 17);
            recs[slot] = (long long)(unsigned)lo |
                         ((long long)__float_as_int(ew[e]) << 32);
            gdst[slot] = (pos < CAP) ? (b * CAP + pos) : -1;  // overflow guard
        }
    }
    __syncthreads();
    int nrec = min(EPB, NE - e0);
    for (int i = tid; i < nrec; i += 256) {
        int gd = gdst[i];
        if (gd >= 0) rec[gd] = recs[i];
    }
}

// ---------- phase B: per-bucket counting sort by (src_slice, dst_local) ----------
// 2048 bins = 4 src-slices x 512 dsts, slice-major: agg phase s gathers from a
// ~2.1 MB dense table slice -> L2-resident (round-2: FETCH 130->66 MB proven).
__global__ __launch_bounds__(256) void kB_sort(const int* __restrict__ gcur,
                                               const int2* __restrict__ rec,
                                               int2* __restrict__ evs,
                                               int* __restrict__ ofs2,
                                               int* __restrict__ cnt4) {
    __shared__ int hist[2048], lofs[2048], ssc[256];
    int tid = threadIdx.x, b = blockIdx.x;
    int nb0 = b << BSH;
    int nnodes = min(512, NN - nb0);
    int cntb = min(gcur[b], CAP);
    for (int i = tid; i < 2048; i += 256) hist[i] = 0;
    __syncthreads();
    const int2* rb = rec + (size_t)b * CAP;
    for (int i = tid; i < cntb; i += 256) {
        int rx = rb[i].x;
        int bin = (((rx & 0x1FFFF) >> 15) << BSH) | ((rx >> 17) & 511);
        atomicAdd(&hist[bin], 1);
    }
    __syncthreads();
    // scan 2048 bins: 8 contiguous bins/thread, block scan of per-thread sums
    int base = tid * 8, ls = 0, lh[8];
#pragma unroll
    for (int j = 0; j < 8; ++j) {
        lh[j] = hist[base + j];
        ls += lh[j];
    }
    ssc[tid] = ls;
    __syncthreads();
    for (int off = 1; off < 256; off <<= 1) {
        int v = (tid >= off) ? ssc[tid - off] : 0;
        __syncthreads();
        ssc[tid] += v;
        __syncthreads();
    }
    int ex = ssc[tid] - ls;
#pragma unroll
    for (int j = 0; j < 8; ++j) {
        lofs[base + j] = ex;
        ex += lh[j];
    }
    __syncthreads();
    // per-node CSR meta: 4 slice starts + packed u8x4 counts
    // (per-(node,slice) degree ~ Poisson(5); max for this input ~25 << 255)
    for (int l = tid; l < nnodes; l += 256) {
        int c0 = hist[l], c1 = hist[512 + l], c2 = hist[1024 + l], c3 = hist[1536 + l];
        cnt4[nb0 + l] = c0 | (c1 << 8) | (c2 << 16) | (c3 << 24);
        ofs2[0 * NN + nb0 + l] = b * CAP + lofs[l];
        ofs2[1 * NN + nb0 + l] = b * CAP + lofs[512 + l];
        ofs2[2 * NN + nb0 + l] = b * CAP + lofs[1024 + l];
        ofs2[3 * NN + nb0 + l] = b * CAP + lofs[1536 + l];
    }
    __syncthreads();
    for (int i = tid; i < 2048; i += 256) hist[i] = 0;
    __syncthreads();
    int2* eb = evs + (size_t)b * CAP;
    for (int i = tid; i < cntb; i += 256) {
        int2 r = rb[i];
        int bin = (((r.x & 0x1FFFF) >> 15) << BSH) | ((r.x >> 17) & 511);
        int rk = atomicAdd(&hist[bin], 1);
        eb[lofs[bin] + rk] = make_int2(r.x & 0x1FFFF, r.y);
    }
}

// ---------- stage 1 of layer-2 weight fold (also zeroes gcur, replaces memset) ----------
__global__ __launch_bounds__(256) void k_wpre(const float* __restrict__ W2m,
                                              const float* __restrict__ wih2,
                                              float* __restrict__ M2,
                                              int* __restrict__ gcur) {
    int i = blockIdx.x * 256 + threadIdx.x;
    if (i < NBK) gcur[i] = 0;
    if (i >= NC * 3 * NC) return;
    int u = i / (3 * NC), col = i % (3 * NC);
    float acc = 0.f;
#pragma unroll
    for (int t = 0; t < NC; ++t) acc += W2m[u * NC + t] * wih2[col * NC + t];
    M2[i] = acc;
}

// ---------- build MFMA B-fragment-linear fp16 weight tables ----------
__global__ __launch_bounds__(256) void k_wc(const float* __restrict__ W1m,
                                            const float* __restrict__ wih1,
                                            const float* __restrict__ W2p,
                                            const float* __restrict__ M2,
                                            const float* __restrict__ whh1,
                                            const float* __restrict__ whh2,
                                            half_t* __restrict__ W1sw,
                                            half_t* __restrict__ W2sw) {
    int i = blockIdx.x * 256 + threadIdx.x;
    if (i < 8192) {
        int j = i & 7, lane = (i >> 3) & 63, ct = (i >> 9) & 7, s = i >> 12;
        int k = s * 32 + (lane >> 4) * 8 + j;
        int col = ct * 16 + (lane & 15);
        int g = col >> 5, jj = col & 31;
        float v = 0.f;
        if (g <= 2) {
            if (k < 32) {  // input side (agg): fold W1m @ wih1^T
                float acc = 0.f;
#pragma unroll
                for (int t = 0; t < H; ++t) acc += W1m[k * H + t] * wih1[(g * H + jj) * H + t];
                v = acc;
            } else if (g < 2) {  // r,z hidden side
                v = whh1[(g * H + jj) * H + (k - 32)];
            }                     // g==2 (i_n), k>=32 -> 0
        } else {                  // g==3 (h_n): hidden side only
            if (k >= 32) v = whh1[(2 * H + jj) * H + (k - 32)];
        }
        W1sw[i] = (half_t)v;
    } else if (i < 8192 + 18432) {
        int i2 = i - 8192;
        int j = i2 & 7, lane = (i2 >> 3) & 63;
        int tt = i2 >> 9;  // 0..35
        int ct = tt % 12, s = tt / 12;
        int k = s * 32 + (lane >> 4) * 8 + j;  // 0..95
        int col = ct * 16 + (lane & 15);       // 0..191
        int g = col / 48, jj = col % 48;
        float v = 0.f;
        if (jj < NC) {
            if (g <= 2) {
                if (k < 32) {  // input side (aggX): W2p @ M2 (stage-1 precomputed)
                    float acc = 0.f;
#pragma unroll
                    for (int u = 0; u < NC; ++u)
                        acc += W2p[k * NC + u] * M2[u * 3 * NC + g * NC + jj];
                    v = acc;
                } else if (k < 72 && g < 2) {  // r,z hidden side
                    v = whh2[(g * NC + jj) * NC + (k - 32)];
                }
            } else {  // g==3 (h_n)
                if (k >= 32 && k < 72) v = whh2[(2 * NC + jj) * NC + (k - 32)];
            }
        }
        W2sw[i2] = (half_t)v;
    }
}

// ---------- K1: h1 = x @ W1p -> fp16 into Xc1 cols 32..63 AND dense Hd [NN][32] ----------
__global__ __launch_bounds__(256) void k1_proj(const float* __restrict__ x,
                                               const float* __restrict__ Wp,
                                               half_t* __restrict__ Xc1,
                                               half_t* __restrict__ Hd) {
    __shared__ float sWp[FIN * H];
    __shared__ float sx[8][FIN];
    int tid = threadIdx.x;
    for (int i = tid; i < FIN * H; i += 256) sWp[i] = Wp[i];
    int nb = blockIdx.x * 8;
    int nl = tid >> 5, j = tid & 31;
    int n = nb + nl;
    if (n < NN) sx[nl][j] = x[(size_t)n * FIN + j];
    __syncthreads();
    float acc = 0.f;
#pragma unroll
    for (int k = 0; k < FIN; ++k) acc += sx[nl][k] * sWp[k * H + j];
    if (n < NN) {
        half_t hv = (half_t)acc;
        Xc1[(size_t)n * 64 + 32 + j] = hv;
        Hd[(size_t)n * 32 + j] = hv;
    }
}

// ---------- K4: h2 = hrelu @ W2p -> fp16 into Xc2 cols 32..71 (stride 96); zero pad 72..95 ----------
__global__ __launch_bounds__(320) void k4_proj2(const half_t* __restrict__ Hh,
                                                const float* __restrict__ Wp,
                                                half_t* __restrict__ Xc2) {
    __shared__ float sWp[FIN * NC];
    __shared__ float shn[8][FIN];
    int tid = threadIdx.x;
    for (int i = tid; i < FIN * NC; i += 320) sWp[i] = Wp[i];
    int nb = blockIdx.x * 8;
    if (tid < 256) {
        int r = tid >> 5, c = tid & 31;
        shn[r][c] = (float)Hh[(size_t)(nb + r) * 32 + c];
    }
    // zero K-pad cols 72..95 (stale scratch can be fp16-NaN; MFMA 0*NaN = NaN)
    if (tid < 192) {
        int r = tid / 24, c = tid % 24;
        Xc2[(size_t)(nb + r) * 96 + 72 + c] = (half_t)0.f;
    }
    __syncthreads();
    int nl = tid / NC, j = tid % NC;
    int n = nb + nl;
    float acc = 0.f;
#pragma unroll
    for (int k = 0; k < FIN; ++k) acc += shn[nl][k] * sWp[k * NC + j];
    if (n < NN) Xc2[(size_t)n * 96 + 32 + j] = (half_t)acc;
}

// ---------- aggregation: slice-segmented fp16 gather, fp32 accum ----------
// Round-16: keep the slice-sorted evs (L2 residency, FETCH 130->66 MB) but drop
// the per-slice barriers that killed MLP (round-2 regression: latency-bound at
// 1.5 TB/s). 4 lanes/node with 16B half8 gathers (half the gather instrs of
// 8-lane/8B, same lines); evs records loaded 2-at-a-time via 16B NT loads with
// head/tail alignment fixup. Slice loop fully unrolled, no syncs: blocks drift
// at most ~1 slice -> 2 adjacent slices (~4.2 MB) still ~fit XCD L2.
template <int DSTR>
__global__ __launch_bounds__(256) void k_aggh(const int* __restrict__ ofs2,
                                              const int* __restrict__ cnt4,
                                              const int2* __restrict__ evs,
                                              const half_t* __restrict__ src,
                                              half_t* __restrict__ dst) {
    int idx = blockIdx.x * 256 + threadIdx.x;
    int n = idx >> 2, q = idx & 3;
    if (n >= NN) return;
    const half8* s8 = (const half8*)src + q;       // 16B column chunk; row stride 4 half8
    const long long* ev8 = (const long long*)evs;  // packed (src, w)
    int cw = cnt4[n];
    float acc[8] = {0.f, 0.f, 0.f, 0.f, 0.f, 0.f, 0.f, 0.f};
#pragma unroll
    for (int s = 0; s < NSL; ++s) {
        int s0 = ofs2[s * NN + n];
        int c = (cw >> (8 * s)) & 255;
        int e = s0, e1 = s0 + c;
        if ((e & 1) && e < e1) {  // head: align to 16B for pair loads
            long long r = __builtin_nontemporal_load(ev8 + e);
            float w = __int_as_float((int)(r >> 32));
            half8 hv = s8[(size_t)(r & 0x1FFFF) * 4];
#pragma unroll
            for (int t = 0; t < 8; ++t) acc[t] += w * (float)hv[t];
            ++e;
        }
        for (; e + 4 <= e1; e += 4) {
            ll2 p0 = __builtin_nontemporal_load((const ll2*)(ev8 + e));
            ll2 p1 = __builtin_nontemporal_load((const ll2*)(ev8 + e + 2));
            half8 h0 = s8[(size_t)(p0[0] & 0x1FFFF) * 4];
            half8 h1 = s8[(size_t)(p0[1] & 0x1FFFF) * 4];
            half8 h2 = s8[(size_t)(p1[0] & 0x1FFFF) * 4];
            half8 h3 = s8[(size_t)(p1[1] & 0x1FFFF) * 4];
            float w0 = __int_as_float((int)(p0[0] >> 32));
            float w1 = __int_as_float((int)(p0[1] >> 32));
            float w2 = __int_as_float((int)(p1[0] >> 32));
            float w3 = __int_as_float((int)(p1[1] >> 32));
#pragma unroll
            for (int t = 0; t < 8; ++t) {
                acc[t] += w0 * (float)h0[t];
                acc[t] += w1 * (float)h1[t];
                acc[t] += w2 * (float)h2[t];
                acc[t] += w3 * (float)h3[t];
            }
        }
        if (e + 2 <= e1) {
            ll2 p0 = __builtin_nontemporal_load((const ll2*)(ev8 + e));
            half8 h0 = s8[(size_t)(p0[0] & 0x1FFFF) * 4];
            half8 h1 = s8[(size_t)(p0[1] & 0x1FFFF) * 4];
            float w0 = __int_as_float((int)(p0[0] >> 32));
            float w1 = __int_as_float((int)(p0[1] >> 32));
#pragma unroll
            for (int t = 0; t < 8; ++t) {
                acc[t] += w0 * (float)h0[t];
                acc[t] += w1 * (float)h1[t];
            }
            e += 2;
        }
        if (e < e1) {  // tail single
            long long r = __builtin_nontemporal_load(ev8 + e);
            float w = __int_as_float((int)(r >> 32));
            half8 hv = s8[(size_t)(r & 0x1FFFF) * 4];
#pragma unroll
            for (int t = 0; t < 8; ++t) acc[t] += w * (float)hv[t];
        }
    }
    half8 o;
#pragma unroll
    for (int t = 0; t < 8; ++t) o[t] = (half_t)acc[t];
    *(half8*)(dst + (size_t)n * DSTR + q * 8) = o;
}

// ---------- K3: GRU layer1 + relu via MFMA. 4 waves x 16 nodes, no LDS ----------
__global__ __launch_bounds__(256) void k3m(const half_t* __restrict__ Xc1,
                                           const half8* __restrict__ W1sw,
                                           const float* __restrict__ bih,
                                           const float* __restrict__ bhh,
                                           half_t* __restrict__ Hh) {
    int tid = threadIdx.x;
    int wave = tid >> 6, lane = tid & 63;
    int m16 = lane & 15, q = lane >> 4;
    int nb = blockIdx.x * 64 + wave * 16;
    const half8* xr = (const half8*)(Xc1 + (size_t)(nb + m16) * 64);
    half8 a0 = xr[q];      // k = q*8..q*8+7
    half8 a1 = xr[4 + q];  // k = 32+q*8..
    f32x4 acc[8];
#pragma unroll
    for (int ct = 0; ct < 8; ++ct) acc[ct] = (f32x4){0.f, 0.f, 0.f, 0.f};
#pragma unroll
    for (int ct = 0; ct < 8; ++ct) {
        acc[ct] = __builtin_amdgcn_mfma_f32_16x16x32_f16(a0, W1sw[ct * 64 + lane], acc[ct], 0, 0, 0);
        acc[ct] = __builtin_amdgcn_mfma_f32_16x16x32_f16(a1, W1sw[(8 + ct) * 64 + lane], acc[ct], 0, 0, 0);
    }
#pragma unroll
    for (int ct = 0; ct < 2; ++ct) {
        int j = ct * 16 + m16;
        float br = bih[j] + bhh[j];
        float bz = bih[H + j] + bhh[H + j];
        float bi = bih[2 * H + j], bh = bhh[2 * H + j];
#pragma unroll
        for (int m = 0; m < 4; ++m) {
            int node = nb + q * 4 + m;  // C/D: row = quad*4 + reg, col = lane&15
            float r = sigm_(acc[ct][m] + br);
            float z = sigm_(acc[2 + ct][m] + bz);
            float ng = tanh_(acc[4 + ct][m] + bi + r * (acc[6 + ct][m] + bh));
            float hj = (float)Xc1[(size_t)node * 64 + 32 + j];
            float o = fmaxf((1.f - z) * ng + z * hj, 0.f);
            if (node < NN) Hh[(size_t)node * 32 + j] = (half_t)o;
        }
    }
}

// ---------- K6: GRU layer2 + log_softmax via MFMA + shfl reduce, no LDS ----------
__global__ __launch_bounds__(256) void k6m(const half_t* __restrict__ Xc2,
                                           const half8* __restrict__ W2sw,
                                           const float* __restrict__ bih,
                                           const float* __restrict__ bhh,
                                           float* __restrict__ out) {
    int tid = threadIdx.x;
    int wave = tid >> 6, lane = tid & 63;
    int m16 = lane & 15, q = lane >> 4;
    int nb = blockIdx.x * 64 + wave * 16;
    const half8* xr = (const half8*)(Xc2 + (size_t)(nb + m16) * 96);
    half8 a0 = xr[q], a1 = xr[4 + q], a2 = xr[8 + q];
    f32x4 acc[12];
#pragma unroll
    for (int ct = 0; ct < 12; ++ct) acc[ct] = (f32x4){0.f, 0.f, 0.f, 0.f};
#pragma unroll
    for (int ct = 0; ct < 12; ++ct) {
        acc[ct] = __builtin_amdgcn_mfma_f32_16x16x32_f16(a0, W2sw[ct * 64 + lane], acc[ct], 0, 0, 0);
        acc[ct] = __builtin_amdgcn_mfma_f32_16x16x32_f16(a1, W2sw[(12 + ct) * 64 + lane], acc[ct], 0, 0, 0);
        acc[ct] = __builtin_amdgcn_mfma_f32_16x16x32_f16(a2, W2sw[(24 + ct) * 64 + lane], acc[ct], 0, 0, 0);
    }
    float v[3][4];
#pragma unroll
    for (int ct = 0; ct < 3; ++ct) {
        int j = ct * 16 + m16;
        int jc = (j < NC) ? j : (NC - 1);  // clamp (lanes with j>=40 produce unused values)
        float br = bih[jc] + bhh[jc];
        float bz = bih[NC + jc] + bhh[NC + jc];
        float bi = bih[2 * NC + jc], bh = bhh[2 * NC + jc];
#pragma unroll
        for (int m = 0; m < 4; ++m) {
            int node = nb + q * 4 + m;
            float r = sigm_(acc[ct][m] + br);
            float z = sigm_(acc[3 + ct][m] + bz);
            float ng = tanh_(acc[6 + ct][m] + bi + r * (acc[9 + ct][m] + bh));
            float hj = (float)Xc2[(size_t)node * 96 + 32 + jc];
            v[ct][m] = (1.f - z) * ng + z * hj;
        }
    }
    bool v2ok = (m16 < 8);  // ct=2 covers j=32..39 only for m16<8
#pragma unroll
    for (int m = 0; m < 4; ++m) {
        float mx = fmaxf(v[0][m], v[1][m]);
        if (v2ok) mx = fmaxf(mx, v[2][m]);
#pragma unroll
        for (int d = 1; d < 16; d <<= 1) mx = fmaxf(mx, __shfl_xor(mx, d));
        float se = __expf(v[0][m] - mx) + __expf(v[1][m] - mx) +
                   (v2ok ? __expf(v[2][m] - mx) : 0.f);
#pragma unroll
        for (int d = 1; d < 16; d <<= 1) se += __shfl_xor(se, d);
        float ls = mx + __logf(se);
        int node = nb + q * 4 + m;
        if (node < NN) {
            out[(size_t)node * NC + m16] = v[0][m] - ls;
            out[(size_t)node * NC + 16 + m16] = v[1][m] - ls;
            if (v2ok) out[(size_t)node * NC + 32 + m16] = v[2][m] - ls;
        }
    }
}

extern "C" void kernel_launch(void* const* d_in, const int* in_sizes, int n_in,
                              void* d_out, int out_size, void* d_ws, size_t ws_size,
                              hipStream_t stream) {
    const float* x = (const float*)d_in[0];
    const int* ei = (const int*)d_in[1];
    const float* ew = (const float*)d_in[2];
    const float* W1p = (const float*)d_in[3];
    const float* W1m = (const float*)d_in[4];
    const float* g1wih = (const float*)d_in[5];
    const float* g1whh = (const float*)d_in[6];
    const float* g1bih = (const float*)d_in[7];
    const float* g1bhh = (const float*)d_in[8];
    const float* W2p = (const float*)d_in[9];
    const float* W2m = (const float*)d_in[10];
    const float* g2wih = (const float*)d_in[11];
    const float* g2whh = (const float*)d_in[12];
    const float* g2bih = (const float*)d_in[13];
    const float* g2bhh = (const float*)d_in[14];
    float* ws = (float*)d_ws;

    // workspace layout (float indices), ~44.7 MB total:
    //  Xc   [0, 4801536)      fp16 activations: [NP][64] L1 / [NP][96] L2
    //  Hd   [3201024,4801536) dense [NN][32] fp16 L1 gather table
    //  Hh   [4801536,6402048) dense [NN][32] fp16 hrelu table
    //  rec  [0, 4264960)      CSR-build scratch, overlays Xc (dead before k1)
    //  evs  [6402048,10667008) 196*CAP sorted records
    //  ofs2 [10667008,11067008) int[4][NN] per-slice segment starts
    //  cnt4 [11067008,11167008) u8x4 per-(node,slice) counts
    //  gcur [11167008,11167264)
    //  W1sw/W2sw/M2 tail
    half_t* Xc = (half_t*)ws;
    half_t* Hd = (half_t*)(ws + 3201024);
    half_t* Hh = (half_t*)(ws + 4801536);
    int2* rec = (int2*)ws;
    int2* evs = (int2*)(ws + 6402048);
    int* ofs2 = (int*)(ws + 10667008);
    int* cnt4 = (int*)(ws + 11067008);
    int* gcur = (int*)(ws + 11167008);
    half_t* W1sw = (half_t*)(ws + 11167264);
    half_t* W2sw = W1sw + 8192;
    float* M2 = ws + 11180576;
    float* out = (float*)d_out;

    // ---- CSR build (shared by both layers) ----
    k_wpre<<<(NC * 3 * NC + 255) / 256, 256, 0, stream>>>(W2m, g2wih, M2, gcur);
    kA_bucket<<<(NE + EPB - 1) / EPB, 256, 0, stream>>>(ei, ew, gcur, (long long*)rec);
    kB_sort<<<NBK, 256, 0, stream>>>(gcur, rec, evs, ofs2, cnt4);
    k_wc<<<(8192 + 18432 + 255) / 256, 256, 0, stream>>>(
        W1m, g1wih, W2p, M2, g1whh, g2whh, W1sw, W2sw);

    // ---- layer 1 ----
    k1_proj<<<NN / 8, 256, 0, stream>>>(x, W1p, Xc, Hd);
    k_aggh<64><<<(NN * 4 + 255) / 256, 256, 0, stream>>>(ofs2, cnt4, evs, Hd, Xc);
    k3m<<<NP / 64, 256, 0, stream>>>(Xc, (const half8*)W1sw, g1bih, g1bhh, Hh);

    // ---- layer 2 ----
    k4_proj2<<<NN / 8, 320, 0, stream>>>(Hh, W2p, Xc);
    k_aggh<96><<<(NN * 4 + 255) / 256, 256, 0, stream>>>(ofs2, cnt4, evs, Hh, Xc);
    k6m<<<NP / 64, 256, 0, stream>>>(Xc, (const half8*)W2sw, g2bih, g2bhh, out);
}